// Round 1
// baseline (322.000 us; speedup 1.0000x reference)
//
#include <hip/hip_runtime.h>
#include <hip/hip_bf16.h>

// Problem constants (Swin window attention)
// B=16, N=1024 (32x32), NH=8, HD=64, DIM=512
// out: [16, 512, 32, 32] fp32

typedef __attribute__((ext_vector_type(4))) float  f32x4;
typedef __attribute__((ext_vector_type(8))) short  s16x8;
typedef __attribute__((ext_vector_type(4))) short  s16x4;

__device__ __forceinline__ short f2bf(float f) {
    union { float f; unsigned u; } v; v.f = f;
    unsigned r = v.u + 0x7fffu + ((v.u >> 16) & 1u);  // RNE
    return (short)(r >> 16);
}
__device__ __forceinline__ float bf2f(short s) {
    union { unsigned u; float f; } v;
    v.u = ((unsigned)(unsigned short)s) << 16;
    return v.f;
}
// Load 8 bf16 from LDS (8B-aligned rows) as two b64 reads
__device__ __forceinline__ s16x8 ld_frag(const short* p) {
    s16x4 lo = *(const s16x4*)p;
    s16x4 hi = *(const s16x4*)(p + 4);
    s16x8 v;
    v[0]=lo[0]; v[1]=lo[1]; v[2]=lo[2]; v[3]=lo[3];
    v[4]=hi[0]; v[5]=hi[1]; v[6]=hi[2]; v[7]=hi[3];
    return v;
}
__device__ __forceinline__ void st8(short* p, s16x8 v) {
    s16x4 lo, hi;
    lo[0]=v[0]; lo[1]=v[1]; lo[2]=v[2]; lo[3]=v[3];
    hi[0]=v[4]; hi[1]=v[5]; hi[2]=v[6]; hi[3]=v[7];
    *(s16x4*)p = lo;
    *(s16x4*)(p + 4) = hi;
}

// ---------------- f32 -> bf16 weight conversion ----------------
__global__ void cvt_kernel(const float* __restrict__ src, short* __restrict__ dst) {
    int i = blockIdx.x * 256 + threadIdx.x;
    f32x4 v = ((const f32x4*)src)[i];
    s16x4 o;
    o[0]=f2bf(v[0]); o[1]=f2bf(v[1]); o[2]=f2bf(v[2]); o[3]=f2bf(v[3]);
    ((s16x4*)dst)[i] = o;
}

// ---------------- bias gather expand: [h][n][m] bf16 ----------------
__global__ void bias_expand(const float* __restrict__ table, const int* __restrict__ ridx,
                            short* __restrict__ out) {
    int i = blockIdx.x * 256 + threadIdx.x;        // 0..1048575 (n*1024+m)
    int idx = ridx[i];
    const float* t = table + idx * 8;
    #pragma unroll
    for (int h = 0; h < 8; h++)
        out[h * 1048576 + i] = f2bf(t[h]);
}

// ---------------- QKV GEMM: [16384,512](f32) x [1536,512]^T -> q,k,vt bf16 ----------------
__global__ __launch_bounds__(256) void qkv_gemm(
    const float* __restrict__ X, const short* __restrict__ W,
    const float* __restrict__ bias,
    short* __restrict__ qb, short* __restrict__ kb, short* __restrict__ vtb)
{
    __shared__ short As[128][36];   // 32 data + 4 pad (conflict-free b64 frag reads)
    __shared__ short Bs[128][36];
    const int tid = threadIdx.x;
    const int lane = tid & 63, w = tid >> 6;
    const int quad = lane >> 4, l16 = lane & 15;
    const int m0 = blockIdx.x * 128, n0 = blockIdx.y * 128;
    const int wm = (w >> 1) * 64, wn = (w & 1) * 64;
    f32x4 acc[4][4] = {};

    const int sr = tid >> 2;         // staging row (64 rows/pass)
    const int sc = (tid & 3) * 8;    // staging col

    for (int k0 = 0; k0 < 512; k0 += 32) {
        __syncthreads();
        #pragma unroll
        for (int p = 0; p < 2; p++) {
            int r = sr + p * 64;
            const f32x4* xs = (const f32x4*)(X + (m0 + r) * 512 + k0 + sc);
            f32x4 f0 = xs[0], f1 = xs[1];
            s16x4 a0, a1;
            a0[0]=f2bf(f0[0]); a0[1]=f2bf(f0[1]); a0[2]=f2bf(f0[2]); a0[3]=f2bf(f0[3]);
            a1[0]=f2bf(f1[0]); a1[1]=f2bf(f1[1]); a1[2]=f2bf(f1[2]); a1[3]=f2bf(f1[3]);
            *(s16x4*)&As[r][sc] = a0;
            *(s16x4*)&As[r][sc + 4] = a1;
            s16x8 wv = *(const s16x8*)(W + (n0 + r) * 512 + k0 + sc);
            st8(&Bs[r][sc], wv);
        }
        __syncthreads();
        s16x8 af[4], bfr[4];
        #pragma unroll
        for (int i = 0; i < 4; i++) af[i]  = ld_frag(&As[wm + i*16 + l16][quad*8]);
        #pragma unroll
        for (int j = 0; j < 4; j++) bfr[j] = ld_frag(&Bs[wn + j*16 + l16][quad*8]);
        #pragma unroll
        for (int i = 0; i < 4; i++)
            #pragma unroll
            for (int j = 0; j < 4; j++)
                acc[i][j] = __builtin_amdgcn_mfma_f32_16x16x32_bf16(af[i], bfr[j], acc[i][j], 0, 0, 0);
    }

    // epilogue: scatter into q (scaled), k [B,NH,N,64], vt [B,NH,64,N]
    #pragma unroll
    for (int j = 0; j < 4; j++) {
        int col = n0 + wn + j*16 + l16;          // 0..1535
        int which = col >> 9, rem = col & 511, h = rem >> 6, d = rem & 63;
        float bv = bias[col];
        #pragma unroll
        for (int i = 0; i < 4; i++) {
            int row = m0 + wm + i*16 + quad*4;   // global row, rows row..row+3
            int bi = row >> 10, n = row & 1023;
            #pragma unroll
            for (int r = 0; r < 4; r++) {
                float v = acc[i][j][r] + bv;
                if (which == 0) {
                    qb[((bi*8 + h)*1024 + n + r)*64 + d] = f2bf(v * 0.125f);
                } else if (which == 1) {
                    kb[((bi*8 + h)*1024 + n + r)*64 + d] = f2bf(v);
                } else {
                    vtb[((bi*8 + h)*64 + d)*1024 + n + r] = f2bf(v);
                }
            }
        }
    }
}

// ---------------- Flash attention per (b,h): S=QK^T+bias, online softmax, O=PV ----------------
__global__ __launch_bounds__(256) void attn_kernel(
    const short* __restrict__ qbuf, const short* __restrict__ kbuf,
    const short* __restrict__ vtbuf, const short* __restrict__ biasb,
    short* __restrict__ ao)
{
    __shared__ short Qs[64][68];      // 64 q-rows x 64 d (+4 pad)
    __shared__ short Ks[128][68];     // 128 k-rows x 64 d
    __shared__ short Vs[64][132];     // 64 d x 128 k (V transposed)
    __shared__ short Ps[4][16][132];  // per-wave P staging (C-layout -> A-layout)

    const int bh = blockIdx.x;              // 0..127
    const int b = bh >> 3, h = bh & 7;
    const int q0 = blockIdx.y * 64;
    const int tid = threadIdx.x, lane = tid & 63, w = tid >> 6;
    const int quad = lane >> 4, l16 = lane & 15;

    const short* qg = qbuf + (bh*1024 + q0) * 64;
    const short* kg = kbuf + bh * 1024 * 64;
    const short* vg = vtbuf + bh * 64 * 1024;

    // stage Q (64x64)
    {
        int r = tid >> 3, c = (tid & 7) * 8;
        #pragma unroll
        for (int p = 0; p < 2; p++) {
            s16x8 v = *(const s16x8*)(qg + (r + p*32)*64 + c);
            st8(&Qs[r + p*32][c], v);
        }
    }
    __syncthreads();
    s16x8 aq[2];
    aq[0] = ld_frag(&Qs[w*16 + l16][quad*8]);
    aq[1] = ld_frag(&Qs[w*16 + l16][32 + quad*8]);

    float mrow[4], lrow[4];
    #pragma unroll
    for (int r = 0; r < 4; r++) { mrow[r] = -1e30f; lrow[r] = 0.f; }
    f32x4 oacc[4] = {};

    for (int it = 0; it < 8; it++) {
        const int k0 = it * 128;
        __syncthreads();
        // stage K (128x64)
        {
            int r = tid >> 3, c = (tid & 7) * 8;
            #pragma unroll
            for (int p = 0; p < 4; p++) {
                s16x8 v = *(const s16x8*)(kg + (k0 + r + p*32)*64 + c);
                st8(&Ks[r + p*32][c], v);
            }
        }
        // stage Vt (64 d x 128 k)
        {
            int r = tid >> 4, c = (tid & 15) * 8;
            #pragma unroll
            for (int p = 0; p < 4; p++) {
                s16x8 v = *(const s16x8*)(vg + (r + p*16)*1024 + k0 + c);
                st8(&Vs[r + p*16][c], v);
            }
        }
        __syncthreads();

        // S = Q K^T  (16 q-rows per wave x 128 cols)
        f32x4 s[8] = {};
        #pragma unroll
        for (int nf = 0; nf < 8; nf++) {
            s16x8 bk0 = ld_frag(&Ks[nf*16 + l16][quad*8]);
            s16x8 bk1 = ld_frag(&Ks[nf*16 + l16][32 + quad*8]);
            s[nf] = __builtin_amdgcn_mfma_f32_16x16x32_bf16(aq[0], bk0, s[nf], 0, 0, 0);
            s[nf] = __builtin_amdgcn_mfma_f32_16x16x32_bf16(aq[1], bk1, s[nf], 0, 0, 0);
        }
        // + relative position bias
        {
            const short* bp = biasb + h*1048576 + (q0 + w*16 + quad*4)*1024 + k0 + l16;
            #pragma unroll
            for (int nf = 0; nf < 8; nf++)
                #pragma unroll
                for (int r = 0; r < 4; r++)
                    s[nf][r] += bf2f(bp[r*1024 + nf*16]);
        }
        // online softmax (row lives in 16 lanes x 8 regs)
        float mnew[4], alpha[4], rs[4];
        #pragma unroll
        for (int r = 0; r < 4; r++) {
            float v = s[0][r];
            #pragma unroll
            for (int nf = 1; nf < 8; nf++) v = fmaxf(v, s[nf][r]);
            #pragma unroll
            for (int off = 1; off < 16; off <<= 1)
                v = fmaxf(v, __shfl_xor(v, off));
            mnew[r] = fmaxf(mrow[r], v);
            alpha[r] = __expf(mrow[r] - mnew[r]);
            mrow[r] = mnew[r];
            rs[r] = 0.f;
        }
        #pragma unroll
        for (int nf = 0; nf < 8; nf++)
            #pragma unroll
            for (int r = 0; r < 4; r++) {
                float p = __expf(s[nf][r] - mnew[r]);
                s[nf][r] = p;
                rs[r] += p;
            }
        #pragma unroll
        for (int r = 0; r < 4; r++) {
            float v = rs[r];
            #pragma unroll
            for (int off = 1; off < 16; off <<= 1)
                v += __shfl_xor(v, off);
            lrow[r] = lrow[r] * alpha[r] + v;
        }
        #pragma unroll
        for (int df = 0; df < 4; df++)
            #pragma unroll
            for (int r = 0; r < 4; r++)
                oacc[df][r] *= alpha[r];

        // P (C-layout) -> LDS -> A-layout
        #pragma unroll
        for (int nf = 0; nf < 8; nf++)
            #pragma unroll
            for (int r = 0; r < 4; r++)
                Ps[w][quad*4 + r][nf*16 + l16] = f2bf(s[nf][r]);
        __syncthreads();

        // O += P @ V
        #pragma unroll
        for (int ks = 0; ks < 4; ks++) {
            s16x8 ap = ld_frag(&Ps[w][l16][ks*32 + quad*8]);
            #pragma unroll
            for (int df = 0; df < 4; df++) {
                s16x8 bv = ld_frag(&Vs[df*16 + l16][ks*32 + quad*8]);
                oacc[df] = __builtin_amdgcn_mfma_f32_16x16x32_bf16(ap, bv, oacc[df], 0, 0, 0);
            }
        }
    }

    // epilogue: ao[b, n, h*64+d] bf16
    #pragma unroll
    for (int df = 0; df < 4; df++)
        #pragma unroll
        for (int r = 0; r < 4; r++) {
            int n = q0 + w*16 + quad*4 + r;
            float o = oacc[df][r] / lrow[r];
            ao[(b*1024 + n)*512 + h*64 + df*16 + l16] = f2bf(o);
        }
}

// ---------------- Proj GEMM: ao[16384,512](bf16) x proj_w^T + b -> out [B,512,1024] fp32 ----------------
__global__ __launch_bounds__(256) void proj_gemm(
    const short* __restrict__ A, const short* __restrict__ W,
    const float* __restrict__ bias, float* __restrict__ out)
{
    __shared__ short As[128][36];
    __shared__ short Bs[128][36];
    const int tid = threadIdx.x;
    const int lane = tid & 63, w = tid >> 6;
    const int quad = lane >> 4, l16 = lane & 15;
    const int m0 = blockIdx.x * 128, n0 = blockIdx.y * 128;
    const int wm = (w >> 1) * 64, wn = (w & 1) * 64;
    f32x4 acc[4][4] = {};

    const int sr = tid >> 2;
    const int sc = (tid & 3) * 8;

    for (int k0 = 0; k0 < 512; k0 += 32) {
        __syncthreads();
        #pragma unroll
        for (int p = 0; p < 2; p++) {
            int r = sr + p * 64;
            s16x8 av = *(const s16x8*)(A + (m0 + r) * 512 + k0 + sc);
            st8(&As[r][sc], av);
            s16x8 wv = *(const s16x8*)(W + (n0 + r) * 512 + k0 + sc);
            st8(&Bs[r][sc], wv);
        }
        __syncthreads();
        s16x8 af[4], bfr[4];
        #pragma unroll
        for (int i = 0; i < 4; i++) af[i]  = ld_frag(&As[wm + i*16 + l16][quad*8]);
        #pragma unroll
        for (int j = 0; j < 4; j++) bfr[j] = ld_frag(&Bs[wn + j*16 + l16][quad*8]);
        #pragma unroll
        for (int i = 0; i < 4; i++)
            #pragma unroll
            for (int j = 0; j < 4; j++)
                acc[i][j] = __builtin_amdgcn_mfma_f32_16x16x32_bf16(af[i], bfr[j], acc[i][j], 0, 0, 0);
    }

    // epilogue: out[b][c][n] = acc + bias[c]  (transposed write)
    #pragma unroll
    for (int j = 0; j < 4; j++) {
        int c = n0 + wn + j*16 + l16;
        float bv = bias[c];
        #pragma unroll
        for (int i = 0; i < 4; i++) {
            int row = m0 + wm + i*16 + quad*4;
            int bi = row >> 10, n = row & 1023;
            #pragma unroll
            for (int r = 0; r < 4; r++)
                out[(bi*512 + c)*1024 + n + r] = acc[i][j][r] + bv;
        }
    }
}

extern "C" void kernel_launch(void* const* d_in, const int* in_sizes, int n_in,
                              void* d_out, int out_size, void* d_ws, size_t ws_size,
                              hipStream_t stream) {
    const float* x      = (const float*)d_in[0];   // [16,1024,512]
    const float* qkv_w  = (const float*)d_in[1];   // [1536,512]
    const float* qkv_b  = (const float*)d_in[2];   // [1536]
    const float* proj_w = (const float*)d_in[3];   // [512,512]
    const float* proj_b = (const float*)d_in[4];   // [512]
    const float* btab   = (const float*)d_in[5];   // [3969,8]
    const int*   ridx   = (const int*)d_in[6];     // [1024,1024]
    float* out = (float*)d_out;

    short* ws    = (short*)d_ws;
    short* wqkv  = ws;                          // 1536*512
    short* wproj = wqkv + 1536*512;             // 512*512
    short* qb    = wproj + 512*512;             // 16*8*1024*64
    short* kb    = qb  + 16*8*1024*64;
    short* vtb   = kb  + 16*8*1024*64;
    short* bx    = vtb + 16*8*1024*64;          // 8*1024*1024
    short* ao    = bx  + 8*1024*1024;           // 16384*512
    // total ~86 MB of workspace

    cvt_kernel<<<768, 256, 0, stream>>>(qkv_w, wqkv);     // 1536*512/1024
    cvt_kernel<<<256, 256, 0, stream>>>(proj_w, wproj);   // 512*512/1024
    bias_expand<<<4096, 256, 0, stream>>>(btab, ridx, bx);
    qkv_gemm<<<dim3(128, 12), 256, 0, stream>>>(x, wqkv, qkv_b, qb, kb, vtb);
    attn_kernel<<<dim3(128, 16), 256, 0, stream>>>(qb, kb, vtb, bx, ao);
    proj_gemm<<<dim3(128, 4), 256, 0, stream>>>(ao, wproj, proj_b, out);
}

// Round 2
// 297.667 us; speedup vs baseline: 1.0817x; 1.0817x over previous
//
#include <hip/hip_runtime.h>
#include <hip/hip_bf16.h>

// Swin window attention: B=16, N=1024 (32x32), NH=8, HD=64, DIM=512
// out: [16, 512, 32, 32] fp32

typedef __attribute__((ext_vector_type(4))) float  f32x4;
typedef __attribute__((ext_vector_type(8))) short  s16x8;
typedef __attribute__((ext_vector_type(4))) short  s16x4;

#define LOG2E 1.44269504f

__device__ __forceinline__ short f2bf(float f) {
    union { float f; unsigned u; } v; v.f = f;
    unsigned r = v.u + 0x7fffu + ((v.u >> 16) & 1u);  // RNE
    return (short)(r >> 16);
}
__device__ __forceinline__ float bf2f(short s) {
    union { unsigned u; float f; } v;
    v.u = ((unsigned)(unsigned short)s) << 16;
    return v.f;
}
__device__ __forceinline__ s16x8 ld_frag(const short* p) {
    s16x4 lo = *(const s16x4*)p;
    s16x4 hi = *(const s16x4*)(p + 4);
    s16x8 v;
    v[0]=lo[0]; v[1]=lo[1]; v[2]=lo[2]; v[3]=lo[3];
    v[4]=hi[0]; v[5]=hi[1]; v[6]=hi[2]; v[7]=hi[3];
    return v;
}
__device__ __forceinline__ void st8(short* p, s16x8 v) {
    s16x4 lo, hi;
    lo[0]=v[0]; lo[1]=v[1]; lo[2]=v[2]; lo[3]=v[3];
    hi[0]=v[4]; hi[1]=v[5]; hi[2]=v[6]; hi[3]=v[7];
    *(s16x4*)p = lo;
    *(s16x4*)(p + 4) = hi;
}

// ---------------- f32 -> bf16 weight conversion ----------------
__global__ void cvt_kernel(const float* __restrict__ src, short* __restrict__ dst) {
    int i = blockIdx.x * 256 + threadIdx.x;
    f32x4 v = ((const f32x4*)src)[i];
    s16x4 o;
    o[0]=f2bf(v[0]); o[1]=f2bf(v[1]); o[2]=f2bf(v[2]); o[3]=f2bf(v[3]);
    ((s16x4*)dst)[i] = o;
}

// ---------------- bias expand, permuted layout [h][n][kblk][l16][nf], *log2e ----------------
__global__ void bias_expand(const float* __restrict__ table, const int* __restrict__ ridx,
                            short* __restrict__ out) {
    int i = blockIdx.x * 256 + threadIdx.x;        // n*1024+m
    int n = i >> 10, m = i & 1023;
    int idx = ridx[i];
    const float* t = table + idx * 8;
    int pos = n * 1024 + (m >> 7) * 128 + (m & 15) * 8 + ((m >> 4) & 7);
    #pragma unroll
    for (int h = 0; h < 8; h++)
        out[h * 1048576 + pos] = f2bf(t[h] * LOG2E);
}

// ---------------- QKV GEMM: [16384,512](f32) x [1536,512]^T -> q,k,vt bf16 ----------------
__global__ __launch_bounds__(256) void qkv_gemm(
    const float* __restrict__ X, const short* __restrict__ W,
    const float* __restrict__ bias,
    short* __restrict__ qb, short* __restrict__ kb, short* __restrict__ vtb)
{
    __shared__ short As[128][36];
    __shared__ short Bs[128][36];
    const int tid = threadIdx.x;
    const int lane = tid & 63, w = tid >> 6;
    const int quad = lane >> 4, l16 = lane & 15;
    const int m0 = blockIdx.x * 128, n0 = blockIdx.y * 128;
    const int wm = (w >> 1) * 64, wn = (w & 1) * 64;
    f32x4 acc[4][4] = {};

    const int sr = tid >> 2;
    const int sc = (tid & 3) * 8;

    for (int k0 = 0; k0 < 512; k0 += 32) {
        __syncthreads();
        #pragma unroll
        for (int p = 0; p < 2; p++) {
            int r = sr + p * 64;
            const f32x4* xs = (const f32x4*)(X + (m0 + r) * 512 + k0 + sc);
            f32x4 f0 = xs[0], f1 = xs[1];
            s16x4 a0, a1;
            a0[0]=f2bf(f0[0]); a0[1]=f2bf(f0[1]); a0[2]=f2bf(f0[2]); a0[3]=f2bf(f0[3]);
            a1[0]=f2bf(f1[0]); a1[1]=f2bf(f1[1]); a1[2]=f2bf(f1[2]); a1[3]=f2bf(f1[3]);
            *(s16x4*)&As[r][sc] = a0;
            *(s16x4*)&As[r][sc + 4] = a1;
            s16x8 wv = *(const s16x8*)(W + (n0 + r) * 512 + k0 + sc);
            st8(&Bs[r][sc], wv);
        }
        __syncthreads();
        s16x8 af[4], bfr[4];
        #pragma unroll
        for (int i = 0; i < 4; i++) af[i]  = ld_frag(&As[wm + i*16 + l16][quad*8]);
        #pragma unroll
        for (int j = 0; j < 4; j++) bfr[j] = ld_frag(&Bs[wn + j*16 + l16][quad*8]);
        #pragma unroll
        for (int i = 0; i < 4; i++)
            #pragma unroll
            for (int j = 0; j < 4; j++)
                acc[i][j] = __builtin_amdgcn_mfma_f32_16x16x32_bf16(af[i], bfr[j], acc[i][j], 0, 0, 0);
    }

    // q scaled by HD^-0.5 * log2e (for exp2-based softmax)
    #pragma unroll
    for (int j = 0; j < 4; j++) {
        int col = n0 + wn + j*16 + l16;
        int which = col >> 9, rem = col & 511, h = rem >> 6, d = rem & 63;
        float bv = bias[col];
        #pragma unroll
        for (int i = 0; i < 4; i++) {
            int row = m0 + wm + i*16 + quad*4;
            int bi = row >> 10, n = row & 1023;
            #pragma unroll
            for (int r = 0; r < 4; r++) {
                float v = acc[i][j][r] + bv;
                if (which == 0) {
                    qb[((bi*8 + h)*1024 + n + r)*64 + d] = f2bf(v * (0.125f * LOG2E));
                } else if (which == 1) {
                    kb[((bi*8 + h)*1024 + n + r)*64 + d] = f2bf(v);
                } else {
                    vtb[((bi*8 + h)*64 + d)*1024 + n + r] = f2bf(v);
                }
            }
        }
    }
}

// ---------------- Flash attention: 512 thr, Q-tile 128, K-tile 128, aliased LDS ----------------
__global__ __launch_bounds__(512, 4) void attn_kernel(
    const short* __restrict__ qbuf, const short* __restrict__ kbuf,
    const short* __restrict__ vtbuf, const short* __restrict__ bxp,
    short* __restrict__ ao)
{
    // R1 (16896 shorts): Qs[128][68] (prologue) / Ks[128][68] (S phase) / Ps 8x[16][132] (PV phase)
    // Vs (8448 shorts):  [64][132]
    __shared__ __align__(16) short smem[25344];   // 50688 B
    short* R1 = smem;
    short* Vs = smem + 16896;

    const int bh = blockIdx.x;              // 0..127
    const int b = bh >> 3, h = bh & 7;
    const int q0 = blockIdx.y * 128;
    const int tid = threadIdx.x, lane = tid & 63, w = tid >> 6;
    const int quad = lane >> 4, l16 = lane & 15;

    const short* qg = qbuf + (bh*1024 + q0) * 64;
    const short* kg = kbuf + bh * 65536;
    const short* vg = vtbuf + bh * 65536;

    // stage Q (128x64) into R1 stride-68
    {
        int r = tid >> 3, c = (tid & 7) * 8;
        #pragma unroll
        for (int p = 0; p < 2; p++)
            st8(&R1[(r + p*64)*68 + c], *(const s16x8*)(qg + (r + p*64)*64 + c));
    }
    __syncthreads();
    s16x8 aq[2];
    aq[0] = ld_frag(&R1[(w*16 + l16)*68 + quad*8]);
    aq[1] = ld_frag(&R1[(w*16 + l16)*68 + 32 + quad*8]);

    float mrow[4], lrow[4];
    #pragma unroll
    for (int r = 0; r < 4; r++) { mrow[r] = -1e30f; lrow[r] = 0.f; }
    f32x4 oacc[4] = {};
    short* Pw = R1 + w * 2112;              // [16][132] per wave

    for (int it = 0; it < 8; it++) {
        const int k0 = it * 128;
        __syncthreads();                    // B1: prev-iter LDS reads done; aq done (it0)

        // bias prefetch: 4 x 16B vector loads (layout [h][n][kblk][l16][nf])
        s16x8 bias_r[4];
        #pragma unroll
        for (int r = 0; r < 4; r++)
            bias_r[r] = *(const s16x8*)(bxp + h*1048576 + (q0 + w*16 + quad*4 + r)*1024 + it*128 + l16*8);

        // stage K (128x64) into R1, V (64x128, transposed) into Vs
        {
            int r = tid >> 3, c = (tid & 7) * 8;
            #pragma unroll
            for (int p = 0; p < 2; p++)
                st8(&R1[(r + p*64)*68 + c], *(const s16x8*)(kg + (k0 + r + p*64)*64 + c));
        }
        {
            int r = tid >> 4, c = (tid & 15) * 8;
            #pragma unroll
            for (int p = 0; p < 2; p++)
                st8(&Vs[(r + p*32)*132 + c], *(const s16x8*)(vg + (r + p*32)*1024 + k0 + c));
        }
        __syncthreads();                    // B2: staging visible

        // S = Q K^T
        f32x4 s[8] = {};
        #pragma unroll
        for (int nf = 0; nf < 8; nf++) {
            s16x8 bk0 = ld_frag(&R1[(nf*16 + l16)*68 + quad*8]);
            s16x8 bk1 = ld_frag(&R1[(nf*16 + l16)*68 + 32 + quad*8]);
            s[nf] = __builtin_amdgcn_mfma_f32_16x16x32_bf16(aq[0], bk0, s[nf], 0, 0, 0);
            s[nf] = __builtin_amdgcn_mfma_f32_16x16x32_bf16(aq[1], bk1, s[nf], 0, 0, 0);
        }
        // + bias (already *log2e)
        #pragma unroll
        for (int nf = 0; nf < 8; nf++)
            #pragma unroll
            for (int r = 0; r < 4; r++)
                s[nf][r] += bf2f(bias_r[r][nf]);

        // online softmax in exp2 domain
        float mnew[4], alpha[4], rs[4];
        #pragma unroll
        for (int r = 0; r < 4; r++) {
            float v = s[0][r];
            #pragma unroll
            for (int nf = 1; nf < 8; nf++) v = fmaxf(v, s[nf][r]);
            #pragma unroll
            for (int off = 1; off < 16; off <<= 1)
                v = fmaxf(v, __shfl_xor(v, off));
            mnew[r] = fmaxf(mrow[r], v);
            alpha[r] = __builtin_exp2f(mrow[r] - mnew[r]);
            mrow[r] = mnew[r];
            rs[r] = 0.f;
        }
        #pragma unroll
        for (int nf = 0; nf < 8; nf++)
            #pragma unroll
            for (int r = 0; r < 4; r++) {
                float p = __builtin_exp2f(s[nf][r] - mnew[r]);
                s[nf][r] = p;
                rs[r] += p;
            }
        #pragma unroll
        for (int r = 0; r < 4; r++) {
            float v = rs[r];
            #pragma unroll
            for (int off = 1; off < 16; off <<= 1)
                v += __shfl_xor(v, off);
            lrow[r] = lrow[r] * alpha[r] + v;
        }
        #pragma unroll
        for (int df = 0; df < 4; df++)
            #pragma unroll
            for (int r = 0; r < 4; r++)
                oacc[df][r] *= alpha[r];

        __syncthreads();                    // B3: all waves done reading Ks; P may overwrite

        // P (C-layout) -> LDS (per-wave region, aliases Ks)
        #pragma unroll
        for (int nf = 0; nf < 8; nf++)
            #pragma unroll
            for (int r = 0; r < 4; r++)
                Pw[(quad*4 + r)*132 + nf*16 + l16] = f2bf(s[nf][r]);
        asm volatile("s_waitcnt lgkmcnt(0)" ::: "memory");  // wave-local visibility, no barrier

        // O += P @ V
        #pragma unroll
        for (int ks = 0; ks < 4; ks++) {
            s16x8 ap = ld_frag(&Pw[l16*132 + ks*32 + quad*8]);
            #pragma unroll
            for (int df = 0; df < 4; df++) {
                s16x8 bv = ld_frag(&Vs[(df*16 + l16)*132 + ks*32 + quad*8]);
                oacc[df] = __builtin_amdgcn_mfma_f32_16x16x32_bf16(ap, bv, oacc[df], 0, 0, 0);
            }
        }
    }

    // epilogue: ao[b, n, h*64+d] bf16
    #pragma unroll
    for (int r = 0; r < 4; r++) {
        int n = q0 + w*16 + quad*4 + r;
        float inv = 1.0f / lrow[r];
        #pragma unroll
        for (int df = 0; df < 4; df++)
            ao[(b*1024 + n)*512 + h*64 + df*16 + l16] = f2bf(oacc[df][r] * inv);
    }
}

// ---------------- Proj GEMM + coalesced transposed epilogue via LDS ----------------
__global__ __launch_bounds__(256) void proj_gemm(
    const short* __restrict__ A, const short* __restrict__ W,
    const float* __restrict__ bias, float* __restrict__ out)
{
    __shared__ __align__(16) short smemp[2*128*36];
    short (*As)[36] = (short(*)[36])smemp;
    short (*Bs)[36] = (short(*)[36])(smemp + 128*36);
    const int tid = threadIdx.x;
    const int lane = tid & 63, w = tid >> 6;
    const int quad = lane >> 4, l16 = lane & 15;
    const int m0 = blockIdx.x * 128, n0 = blockIdx.y * 128;
    const int wm = (w >> 1) * 64, wn = (w & 1) * 64;
    f32x4 acc[4][4] = {};

    const int sr = tid >> 2;
    const int sc = (tid & 3) * 8;

    for (int k0 = 0; k0 < 512; k0 += 32) {
        __syncthreads();
        #pragma unroll
        for (int p = 0; p < 2; p++) {
            int r = sr + p * 64;
            s16x8 av = *(const s16x8*)(A + (m0 + r) * 512 + k0 + sc);
            st8(&As[r][sc], av);
            s16x8 wv = *(const s16x8*)(W + (n0 + r) * 512 + k0 + sc);
            st8(&Bs[r][sc], wv);
        }
        __syncthreads();
        s16x8 af[4], bfr[4];
        #pragma unroll
        for (int i = 0; i < 4; i++) af[i]  = ld_frag(&As[wm + i*16 + l16][quad*8]);
        #pragma unroll
        for (int j = 0; j < 4; j++) bfr[j] = ld_frag(&Bs[wn + j*16 + l16][quad*8]);
        #pragma unroll
        for (int i = 0; i < 4; i++)
            #pragma unroll
            for (int j = 0; j < 4; j++)
                acc[i][j] = __builtin_amdgcn_mfma_f32_16x16x32_bf16(af[i], bfr[j], acc[i][j], 0, 0, 0);
    }

    // epilogue: LDS transpose -> coalesced out[b][c][n] writes (512B rows)
    const int bi = m0 >> 10, nbase = m0 & 1023;
    float* Ts = (float*)smemp;              // [32][132] f32 = 16896 B <= 18432 B
    #pragma unroll
    for (int ci = 0; ci < 4; ci++) {
        __syncthreads();
        if ((w & 1) == (ci >> 1)) {
            #pragma unroll
            for (int jj = 0; jj < 2; jj++) {
                int j = (ci & 1) * 2 + jj;
                int c = n0 + wn + j*16 + l16;
                float bv = bias[c];
                int cl = jj*16 + l16;
                #pragma unroll
                for (int i = 0; i < 4; i++) {
                    f32x4 v = acc[i][j];
                    v[0] += bv; v[1] += bv; v[2] += bv; v[3] += bv;
                    *(f32x4*)&Ts[cl*132 + wm + i*16 + quad*4] = v;
                }
            }
        }
        __syncthreads();
        #pragma unroll
        for (int p = 0; p < 4; p++) {
            int row = (tid >> 5) + p*8, col = (tid & 31)*4;
            f32x4 v = *(const f32x4*)&Ts[row*132 + col];
            *(f32x4*)&out[(bi*512 + n0 + ci*32 + row)*1024 + nbase + col] = v;
        }
    }
}

extern "C" void kernel_launch(void* const* d_in, const int* in_sizes, int n_in,
                              void* d_out, int out_size, void* d_ws, size_t ws_size,
                              hipStream_t stream) {
    const float* x      = (const float*)d_in[0];   // [16,1024,512]
    const float* qkv_w  = (const float*)d_in[1];   // [1536,512]
    const float* qkv_b  = (const float*)d_in[2];   // [1536]
    const float* proj_w = (const float*)d_in[3];   // [512,512]
    const float* proj_b = (const float*)d_in[4];   // [512]
    const float* btab   = (const float*)d_in[5];   // [3969,8]
    const int*   ridx   = (const int*)d_in[6];     // [1024,1024]
    float* out = (float*)d_out;

    short* ws    = (short*)d_ws;
    short* wqkv  = ws;                          // 1536*512
    short* wproj = wqkv + 1536*512;             // 512*512
    short* qb    = wproj + 512*512;             // 16*8*1024*64
    short* kb    = qb  + 16*8*1024*64;
    short* vtb   = kb  + 16*8*1024*64;
    short* bx    = vtb + 16*8*1024*64;          // 8*1024*1024 (permuted, *log2e)
    short* ao    = bx  + 8*1024*1024;           // 16384*512

    cvt_kernel<<<768, 256, 0, stream>>>(qkv_w, wqkv);
    cvt_kernel<<<256, 256, 0, stream>>>(proj_w, wproj);
    bias_expand<<<4096, 256, 0, stream>>>(btab, ridx, bx);
    qkv_gemm<<<dim3(128, 12), 256, 0, stream>>>(x, wqkv, qkv_b, qb, kb, vtb);
    attn_kernel<<<dim3(128, 8), 512, 0, stream>>>(qb, kb, vtb, bx, ao);
    proj_gemm<<<dim3(128, 4), 256, 0, stream>>>(ao, wproj, proj_b, out);
}

// Round 3
// 263.580 us; speedup vs baseline: 1.2216x; 1.1293x over previous
//
#include <hip/hip_runtime.h>
#include <hip/hip_bf16.h>

// Swin window attention: B=16, N=1024 (32x32), NH=8, HD=64, DIM=512
// out: [16, 512, 32, 32] fp32

typedef __attribute__((ext_vector_type(4))) float  f32x4;
typedef __attribute__((ext_vector_type(8))) short  s16x8;
typedef __attribute__((ext_vector_type(4))) short  s16x4;

#define LOG2E 1.44269504f

__device__ __forceinline__ short f2bf(float f) {
    union { float f; unsigned u; } v; v.f = f;
    unsigned r = v.u + 0x7fffu + ((v.u >> 16) & 1u);  // RNE
    return (short)(r >> 16);
}
__device__ __forceinline__ float u2f(unsigned u) {
    union { unsigned u; float f; } v; v.u = u; return v.f;
}
__device__ __forceinline__ unsigned f2u(float f) {
    union { float f; unsigned u; } v; v.f = f; return v.u;
}
// RNE-pack two f32 -> packed bf16x2 (lo=a, hi=b) via v_perm
__device__ __forceinline__ unsigned pack2(float a, float b) {
    unsigned ua = f2u(a), ub = f2u(b);
    ua += 0x7fffu + ((ua >> 16) & 1u);
    ub += 0x7fffu + ((ub >> 16) & 1u);
    return __builtin_amdgcn_perm(ub, ua, 0x07060302);
}
__device__ __forceinline__ s16x8 ld_frag(const short* p) {
    s16x4 lo = *(const s16x4*)p;
    s16x4 hi = *(const s16x4*)(p + 4);
    s16x8 v;
    v[0]=lo[0]; v[1]=lo[1]; v[2]=lo[2]; v[3]=lo[3];
    v[4]=hi[0]; v[5]=hi[1]; v[6]=hi[2]; v[7]=hi[3];
    return v;
}
__device__ __forceinline__ void st8(short* p, s16x8 v) {
    s16x4 lo, hi;
    lo[0]=v[0]; lo[1]=v[1]; lo[2]=v[2]; lo[3]=v[3];
    hi[0]=v[4]; hi[1]=v[5]; hi[2]=v[6]; hi[3]=v[7];
    *(s16x4*)p = lo;
    *(s16x4*)(p + 4) = hi;
}

// ---------------- f32 -> bf16 conversion ----------------
__global__ void cvt_kernel(const float* __restrict__ src, short* __restrict__ dst) {
    int i = blockIdx.x * 256 + threadIdx.x;
    f32x4 v = ((const f32x4*)src)[i];
    s16x4 o;
    o[0]=f2bf(v[0]); o[1]=f2bf(v[1]); o[2]=f2bf(v[2]); o[3]=f2bf(v[3]);
    ((s16x4*)dst)[i] = o;
}

// ---------------- bias expand: C-init layout [h][q][it][quad][nf][r] bf16, *log2e ----------------
__global__ void bias_expand(const float* __restrict__ table, const int* __restrict__ ridx,
                            short* __restrict__ out) {
    int i = blockIdx.x * 256 + threadIdx.x;        // q*1024 + k
    int n = i >> 10, m = i & 1023;
    int idx = ridx[i];
    const float* t = table + idx * 8;
    int pos = ((n*8 + (m >> 7))*4 + ((m >> 2) & 3))*32 + ((m >> 4) & 7)*4 + (m & 3);
    #pragma unroll
    for (int h = 0; h < 8; h++)
        out[h * 1048576 + pos] = f2bf(t[h] * LOG2E);
}

// ---------------- QKV GEMM: Xb[16384,512](bf16) x W[1536,512]^T -> q,k,vt bf16 ----------------
__global__ __launch_bounds__(256) void qkv_gemm(
    const short* __restrict__ Xb, const short* __restrict__ W,
    const float* __restrict__ bias,
    short* __restrict__ qb, short* __restrict__ kb, short* __restrict__ vtb)
{
    __shared__ short As[128][36];
    __shared__ short Bs[128][36];
    const int tid = threadIdx.x;
    const int lane = tid & 63, w = tid >> 6;
    const int quad = lane >> 4, l16 = lane & 15;
    const int m0 = blockIdx.y * 128, n0 = blockIdx.x * 128;
    const int wm = (w >> 1) * 64, wn = (w & 1) * 64;
    f32x4 acc[4][4] = {};

    const int sr = tid >> 2;
    const int sc = (tid & 3) * 8;

    for (int k0 = 0; k0 < 512; k0 += 32) {
        __syncthreads();
        #pragma unroll
        for (int p = 0; p < 2; p++) {
            int r = sr + p * 64;
            st8(&As[r][sc], *(const s16x8*)(Xb + (m0 + r) * 512 + k0 + sc));
            st8(&Bs[r][sc], *(const s16x8*)(W  + (n0 + r) * 512 + k0 + sc));
        }
        __syncthreads();
        s16x8 af[4], bfr[4];
        #pragma unroll
        for (int i = 0; i < 4; i++) af[i]  = ld_frag(&As[wm + i*16 + l16][quad*8]);
        #pragma unroll
        for (int j = 0; j < 4; j++) bfr[j] = ld_frag(&Bs[wn + j*16 + l16][quad*8]);
        #pragma unroll
        for (int i = 0; i < 4; i++)
            #pragma unroll
            for (int j = 0; j < 4; j++)
                acc[i][j] = __builtin_amdgcn_mfma_f32_16x16x32_bf16(af[i], bfr[j], acc[i][j], 0, 0, 0);
    }

    #pragma unroll
    for (int j = 0; j < 4; j++) {
        int col = n0 + wn + j*16 + l16;
        int which = col >> 9, rem = col & 511, h = rem >> 6, d = rem & 63;
        float bv = bias[col];
        #pragma unroll
        for (int i = 0; i < 4; i++) {
            int row = m0 + wm + i*16 + quad*4;
            int bi = row >> 10, n = row & 1023;
            if (which == 2) {
                float v0 = acc[i][j][0] + bv, v1 = acc[i][j][1] + bv;
                float v2 = acc[i][j][2] + bv, v3 = acc[i][j][3] + bv;
                uint2 pk; pk.x = pack2(v0, v1); pk.y = pack2(v2, v3);
                *(uint2*)&vtb[((bi*8 + h)*64 + d)*1024 + n] = pk;
            } else {
                #pragma unroll
                for (int r = 0; r < 4; r++) {
                    float v = acc[i][j][r] + bv;
                    if (which == 0)
                        qb[((bi*8 + h)*1024 + n + r)*64 + d] = f2bf(v * (0.125f * LOG2E));
                    else
                        kb[((bi*8 + h)*1024 + n + r)*64 + d] = f2bf(v);
                }
            }
        }
    }
}

// ---------------- Flash attention (S^T form): 512 thr, Q-tile 128, K-tile 128 ----------------
__global__ __launch_bounds__(512, 4) void attn_kernel(
    const short* __restrict__ qbuf, const short* __restrict__ kbuf,
    const short* __restrict__ vtbuf, const short* __restrict__ bxp,
    short* __restrict__ ao)
{
    // R1 (16896 shorts): Qs[128][68] (prologue) / Ks[128][68] (S phase) / Ps 8x[16][132] (PV phase)
    // Vs (8448 shorts):  [64][132]
    __shared__ __align__(16) short smem[25344];   // 50688 B
    short* R1 = smem;
    short* Vs = smem + 16896;

    const int bh = blockIdx.y;              // 0..127
    const int b = bh >> 3, h = bh & 7;
    const int q0 = blockIdx.x * 128;
    const int tid = threadIdx.x, lane = tid & 63, w = tid >> 6;
    const int quad = lane >> 4, l16 = lane & 15;

    const short* qg = qbuf + (bh*1024 + q0) * 64;
    const short* kg = kbuf + bh * 65536;
    const short* vg = vtbuf + bh * 65536;

    // stage Q (128x64)
    {
        int r = tid >> 3, c = (tid & 7) * 8;
        #pragma unroll
        for (int p = 0; p < 2; p++)
            st8(&R1[(r + p*64)*68 + c], *(const s16x8*)(qg + (r + p*64)*64 + c));
    }
    __syncthreads();
    s16x8 aq[2];                            // B-frag: n = l16 = wave's q row
    aq[0] = ld_frag(&R1[(w*16 + l16)*68 + quad*8]);
    aq[1] = ld_frag(&R1[(w*16 + l16)*68 + 32 + quad*8]);

    float mrow = -1e30f, lrow = 0.f;        // per-lane: q = q0 + w*16 + l16
    f32x4 oacc[4] = {};
    short* Pw = R1 + w * 2112;              // [16 q][132 k] per wave
    const short* bbase = bxp + h*1048576 + ((q0 + w*16 + l16)*8)*128 + quad*32;

    for (int it = 0; it < 8; it++) {
        const int k0 = it * 128;
        __syncthreads();                    // B1: prev-iter LDS reads done

        // bias C-init: 4 x 16B loads (32 bf16, this lane's [nf][r] slice)
        uint4 bw[4];
        {
            const uint4* bp = (const uint4*)(bbase + it*128);
            #pragma unroll
            for (int j = 0; j < 4; j++) bw[j] = bp[j];
        }

        // stage K (128x64) into R1, V^T (64 d x 128 k) into Vs
        {
            int r = tid >> 3, c = (tid & 7) * 8;
            #pragma unroll
            for (int p = 0; p < 2; p++)
                st8(&R1[(r + p*64)*68 + c], *(const s16x8*)(kg + (k0 + r + p*64)*64 + c));
        }
        {
            int r = tid >> 4, c = (tid & 15) * 8;
            #pragma unroll
            for (int p = 0; p < 2; p++)
                st8(&Vs[(r + p*32)*132 + c], *(const s16x8*)(vg + (r + p*32)*1024 + k0 + c));
        }
        __syncthreads();                    // B2: staging visible

        // S^T = K Q^T, C initialized with bias. s[nf][r]: k = nf*16+quad*4+r, q = l16
        f32x4 s[8];
        #pragma unroll
        for (int nf = 0; nf < 8; nf++) {
            unsigned ua = (nf & 1) ? bw[nf >> 1].z : bw[nf >> 1].x;
            unsigned ub = (nf & 1) ? bw[nf >> 1].w : bw[nf >> 1].y;
            s[nf][0] = u2f(ua << 16); s[nf][1] = u2f(ua & 0xffff0000u);
            s[nf][2] = u2f(ub << 16); s[nf][3] = u2f(ub & 0xffff0000u);
            s16x8 bk0 = ld_frag(&R1[(nf*16 + l16)*68 + quad*8]);
            s16x8 bk1 = ld_frag(&R1[(nf*16 + l16)*68 + 32 + quad*8]);
            s[nf] = __builtin_amdgcn_mfma_f32_16x16x32_bf16(bk0, aq[0], s[nf], 0, 0, 0);
            s[nf] = __builtin_amdgcn_mfma_f32_16x16x32_bf16(bk1, aq[1], s[nf], 0, 0, 0);
        }

        // online softmax over k: 32 in-lane values + 2 cross-quad shuffles
        float mx = s[0][0];
        #pragma unroll
        for (int nf = 0; nf < 8; nf++) {
            float a = fmaxf(s[nf][0], s[nf][1]), c = fmaxf(s[nf][2], s[nf][3]);
            mx = fmaxf(mx, fmaxf(a, c));
        }
        mx = fmaxf(mx, __shfl_xor(mx, 16));
        mx = fmaxf(mx, __shfl_xor(mx, 32));
        float mnew = fmaxf(mrow, mx);
        float alpha = __builtin_exp2f(mrow - mnew);
        mrow = mnew;
        float rs = 0.f;
        #pragma unroll
        for (int nf = 0; nf < 8; nf++)
            #pragma unroll
            for (int r = 0; r < 4; r++) {
                float p = __builtin_exp2f(s[nf][r] - mnew);
                s[nf][r] = p;
                rs += p;
            }
        rs += __shfl_xor(rs, 16);
        rs += __shfl_xor(rs, 32);
        lrow = lrow * alpha + rs;

        // rescale O: alpha for q_local = quad*4 + r (broadcast from lanes 0..15)
        float a_r[4];
        #pragma unroll
        for (int r = 0; r < 4; r++) a_r[r] = __shfl(alpha, quad*4 + r);
        #pragma unroll
        for (int df = 0; df < 4; df++)
            #pragma unroll
            for (int r = 0; r < 4; r++)
                oacc[df][r] *= a_r[r];

        __syncthreads();                    // B3: all waves done with Ks; P may overwrite

        // P pack + store: per nf one b64 (4 k-contiguous bf16 at row q=l16)
        #pragma unroll
        for (int nf = 0; nf < 8; nf++) {
            uint2 pk;
            pk.x = pack2(s[nf][0], s[nf][1]);
            pk.y = pack2(s[nf][2], s[nf][3]);
            *(uint2*)&Pw[l16*132 + nf*16 + quad*4] = pk;
        }
        asm volatile("s_waitcnt lgkmcnt(0)" ::: "memory");  // wave-local visibility

        // O += P @ V   (A = P[q][k], B = V^T[d][k])
        #pragma unroll
        for (int ks = 0; ks < 4; ks++) {
            s16x8 ap = ld_frag(&Pw[l16*132 + ks*32 + quad*8]);
            #pragma unroll
            for (int df = 0; df < 4; df++) {
                s16x8 bv = ld_frag(&Vs[(df*16 + l16)*132 + ks*32 + quad*8]);
                oacc[df] = __builtin_amdgcn_mfma_f32_16x16x32_bf16(ap, bv, oacc[df], 0, 0, 0);
            }
        }
    }

    // epilogue: O row = q_local quad*4+r, col d = df*16+l16
    float inv_r[4];
    #pragma unroll
    for (int r = 0; r < 4; r++) inv_r[r] = 1.0f / __shfl(lrow, quad*4 + r);
    #pragma unroll
    for (int r = 0; r < 4; r++) {
        int n = q0 + w*16 + quad*4 + r;
        #pragma unroll
        for (int df = 0; df < 4; df++)
            ao[(b*1024 + n)*512 + h*64 + df*16 + l16] = f2bf(oacc[df][r] * inv_r[r]);
    }
}

// ---------------- Proj GEMM + coalesced transposed epilogue via LDS ----------------
__global__ __launch_bounds__(256) void proj_gemm(
    const short* __restrict__ A, const short* __restrict__ W,
    const float* __restrict__ bias, float* __restrict__ out)
{
    __shared__ __align__(16) short smemp[2*128*36];
    short (*As)[36] = (short(*)[36])smemp;
    short (*Bs)[36] = (short(*)[36])(smemp + 128*36);
    const int tid = threadIdx.x;
    const int lane = tid & 63, w = tid >> 6;
    const int quad = lane >> 4, l16 = lane & 15;
    const int m0 = blockIdx.y * 128, n0 = blockIdx.x * 128;
    const int wm = (w >> 1) * 64, wn = (w & 1) * 64;
    f32x4 acc[4][4] = {};

    const int sr = tid >> 2;
    const int sc = (tid & 3) * 8;

    for (int k0 = 0; k0 < 512; k0 += 32) {
        __syncthreads();
        #pragma unroll
        for (int p = 0; p < 2; p++) {
            int r = sr + p * 64;
            st8(&As[r][sc], *(const s16x8*)(A + (m0 + r) * 512 + k0 + sc));
            st8(&Bs[r][sc], *(const s16x8*)(W + (n0 + r) * 512 + k0 + sc));
        }
        __syncthreads();
        s16x8 af[4], bfr[4];
        #pragma unroll
        for (int i = 0; i < 4; i++) af[i]  = ld_frag(&As[wm + i*16 + l16][quad*8]);
        #pragma unroll
        for (int j = 0; j < 4; j++) bfr[j] = ld_frag(&Bs[wn + j*16 + l16][quad*8]);
        #pragma unroll
        for (int i = 0; i < 4; i++)
            #pragma unroll
            for (int j = 0; j < 4; j++)
                acc[i][j] = __builtin_amdgcn_mfma_f32_16x16x32_bf16(af[i], bfr[j], acc[i][j], 0, 0, 0);
    }

    // epilogue: LDS transpose -> coalesced out[b][c][n] writes
    const int bi = m0 >> 10, nbase = m0 & 1023;
    float* Ts = (float*)smemp;              // [32][132] f32
    #pragma unroll
    for (int ci = 0; ci < 4; ci++) {
        __syncthreads();
        if ((w & 1) == (ci >> 1)) {
            #pragma unroll
            for (int jj = 0; jj < 2; jj++) {
                int j = (ci & 1) * 2 + jj;
                int c = n0 + wn + j*16 + l16;
                float bv = bias[c];
                int cl = jj*16 + l16;
                #pragma unroll
                for (int i = 0; i < 4; i++) {
                    f32x4 v = acc[i][j];
                    v[0] += bv; v[1] += bv; v[2] += bv; v[3] += bv;
                    *(f32x4*)&Ts[cl*132 + wm + i*16 + quad*4] = v;
                }
            }
        }
        __syncthreads();
        #pragma unroll
        for (int p = 0; p < 4; p++) {
            int row = (tid >> 5) + p*8, col = (tid & 31)*4;
            f32x4 v = *(const f32x4*)&Ts[row*132 + col];
            *(f32x4*)&out[(bi*512 + n0 + ci*32 + row)*1024 + nbase + col] = v;
        }
    }
}

extern "C" void kernel_launch(void* const* d_in, const int* in_sizes, int n_in,
                              void* d_out, int out_size, void* d_ws, size_t ws_size,
                              hipStream_t stream) {
    const float* x      = (const float*)d_in[0];   // [16,1024,512]
    const float* qkv_w  = (const float*)d_in[1];   // [1536,512]
    const float* qkv_b  = (const float*)d_in[2];   // [1536]
    const float* proj_w = (const float*)d_in[3];   // [512,512]
    const float* proj_b = (const float*)d_in[4];   // [512]
    const float* btab   = (const float*)d_in[5];   // [3969,8]
    const int*   ridx   = (const int*)d_in[6];     // [1024,1024]
    float* out = (float*)d_out;

    short* ws    = (short*)d_ws;
    short* wqkv  = ws;                          // 1536*512
    short* wproj = wqkv + 1536*512;             // 512*512
    short* qb    = wproj + 512*512;             // 16*8*1024*64
    short* kb    = qb  + 16*8*1024*64;
    short* vtb   = kb  + 16*8*1024*64;
    short* bx    = vtb + 16*8*1024*64;          // 8*1024*1024 (C-init layout, *log2e)
    short* ao    = bx  + 8*1024*1024;           // 16384*512 ; also reused as bf16-X before attn
    short* xb    = ao;                          // alias: X(bf16) lives here until attn writes ao

    cvt_kernel<<<8192, 256, 0, stream>>>(x, xb);          // X f32 -> bf16
    cvt_kernel<<<768, 256, 0, stream>>>(qkv_w, wqkv);
    cvt_kernel<<<256, 256, 0, stream>>>(proj_w, wproj);
    bias_expand<<<4096, 256, 0, stream>>>(btab, ridx, bx);
    qkv_gemm<<<dim3(12, 128), 256, 0, stream>>>(xb, wqkv, qkv_b, qb, kb, vtb);
    attn_kernel<<<dim3(8, 128), 512, 0, stream>>>(qb, kb, vtb, bx, ao);
    proj_gemm<<<dim3(4, 128), 256, 0, stream>>>(ao, wproj, proj_b, out);
}